// Round 15
// baseline (12011.797 us; speedup 1.0000x reference)
//
#include <hip/hip_runtime.h>
#include <hip/hip_bf16.h>
#include <stdint.h>

// ---- problem dims (fixed by setup_inputs) ----
#define DIM   4096
#define HID   11008
#define MTOK  4096              // B*S = 2*2048
#define NELW  (HID * DIM)       // 45,088,768 elements per weight matrix

typedef __bf16 bf16x8 __attribute__((ext_vector_type(8)));
typedef float  f32x4  __attribute__((ext_vector_type(4)));
using gptr_t = const __attribute__((address_space(1))) void*;
using lptr_t = __attribute__((address_space(3))) void*;

__device__ __forceinline__ float bf2f(unsigned short u) {
    unsigned int t = ((unsigned int)u) << 16;
    float f; __builtin_memcpy(&f, &t, 4); return f;
}
__device__ __forceinline__ unsigned short f2bf(float f) {   // RNE
    unsigned int x; __builtin_memcpy(&x, &f, 4);
    x += 0x7fffu + ((x >> 16) & 1u);
    return (unsigned short)(x >> 16);
}

__device__ __constant__ float NF4_TAB[16] = {
    -1.0f, -0.6961928009986877f, -0.5250730514526367f, -0.39491748809814453f,
    -0.28444138169288635f, -0.18477343022823334f, -0.09105003625154495f, 0.0f,
    0.07958029955625534f, 0.16093020141124725f, 0.24611230194568634f,
    0.33791524171829224f, 0.44070982933044434f, 0.5626170039176941f,
    0.6989939212799072f, 1.0f};

// dequant 8 codes at element offset `base` (table via wave shfl from lanes 0-15)
__device__ __forceinline__ void dq8(const int* codes, const float* absmax,
                                    unsigned short* out, long base, float tv)
{
    int4 c0 = *(const int4*)(codes + base);
    int4 c1 = *(const int4*)(codes + base + 4);
    float s = absmax[base >> 6];
    union { uint4 q; unsigned short u[8]; } o;
    o.u[0] = f2bf(__shfl(tv, c0.x) * s);
    o.u[1] = f2bf(__shfl(tv, c0.y) * s);
    o.u[2] = f2bf(__shfl(tv, c0.z) * s);
    o.u[3] = f2bf(__shfl(tv, c0.w) * s);
    o.u[4] = f2bf(__shfl(tv, c1.x) * s);
    o.u[5] = f2bf(__shfl(tv, c1.y) * s);
    o.u[6] = f2bf(__shfl(tv, c1.z) * s);
    o.u[7] = f2bf(__shfl(tv, c1.w) * s);
    *(uint4*)(out + base) = o.q;
}

// preamble: blocks [0, 22016) dequant W1; blocks [22016, 30208) cast x->bf16
#define W1BLK 22016
#define PREBLK (W1BLK + (MTOK * DIM) / 2048)
__global__ __launch_bounds__(256) void pre_k(
    const int* __restrict__ w1c, const float* __restrict__ w1a,
    unsigned short* __restrict__ W1,
    const float* __restrict__ x, unsigned short* __restrict__ Xb)
{
    float tv = NF4_TAB[threadIdx.x & 15];
    if ((int)blockIdx.x < W1BLK) {
        long base = ((long)blockIdx.x * 256 + threadIdx.x) * 8;
        dq8(w1c, w1a, W1, base, tv);
    } else {
        long base = ((long)(blockIdx.x - W1BLK) * 256 + threadIdx.x) * 8;
        float4 a = *(const float4*)(x + base);
        float4 b = *(const float4*)(x + base + 4);
        union { uint4 q; unsigned short u[8]; } o;
        o.u[0] = f2bf(a.x); o.u[1] = f2bf(a.y); o.u[2] = f2bf(a.z); o.u[3] = f2bf(a.w);
        o.u[4] = f2bf(b.x); o.u[5] = f2bf(b.y); o.u[6] = f2bf(b.z); o.u[7] = f2bf(b.w);
        *(uint4*)(Xb + base) = o.q;
    }
}

// ============================================================================
// 256x256-tile GEMM, R15: R10's schedule at BK=32 -> 64KB LDS -> 2 blocks/CU.
//
// Mechanism (m114): two co-resident INDEPENDENT blocks per CU co-schedule the
// MFMA and DS pipes (block A's MFMA phase overlaps block B's read phase) —
// the cross-pipe overlap that 1-block/CU barrier-aligned waves cannot get,
// and that intra-block scheduling (R5/R9/R10/R11-R13) failed to produce.
//
// All R10 ledger constants halved (STAGE = ONE 8KB global_load_lds):
//   prologue: tile0 A0,A1,B0,B1 -> buf0; tile1 A0,A1 -> buf1 (6 loads);
//     vmcnt(2) lands tile0's 4; BAR; LDA(a0,0,0).
//   iter t: P1 stage B0[t+1]->nb, P2 B1[t+1]->nb, P3 A0[t+2]->cur + vmcnt(3)
//     publishes A[t+1], P4 A1[t+2]->cur + vmcnt(2) publishes B[t+1].
//     In-flight never <2 (T4).
//   Region liveness (regions = M-half for A, N-pair for B): P3's A0-stage
//     1 barrier after P2's a1-consuming MMA drain; P4's A1-stage likewise;
//     P1/P2 B-stages -> buf[nb] B-regions dead since t-1 P3; P4's a0[t+1]
//     read follows P3's vmcnt(3)+BAR publish.  Tail clamps land dead.
//   Swizzle at 4 chunks/row: LDS[r][c] = G[r][c ^ (r&3)]; read chunk
//     hi ^ (lrow&3).  Bank map: even/odd rows use disjoint 16-bank halves,
//     4 chunk positions x 4 banks, 2 lanes/bank = conflict-free (m136).
//
// __launch_bounds__(512,4): cap VGPR <=128 so 4 waves/SIMD (2 blocks) fit.
// Blocks >= ngemm run grid-stride NF4 dequant (dqc/dqa->dqo) -- tail fill;
// consumer is the NEXT dispatch (dispatch boundary = fence).
// MODE: 0 = f32 out, 1 = bf16 out, 2 = bf16 fused h=silu(Cout)*acc in-place.
// ============================================================================
template<int MODE>
__global__ __launch_bounds__(512, 4) void gemm256_k(
    const unsigned short* __restrict__ A, const unsigned short* __restrict__ B,
    void* __restrict__ Cout, int M, int N, int K, int ngemm,
    const int* __restrict__ dqc, const float* __restrict__ dqa,
    unsigned short* __restrict__ dqo)
{
    __shared__ __align__(16) unsigned short lds[2][2][2][128 * 32];

    const int tid = threadIdx.x;
    const int lane = tid & 63;

    if ((int)blockIdx.x >= ngemm) {          // ---- tail: grid-stride dequant
        if (!dqo) return;
        const int b = (int)blockIdx.x - ngemm;
        const int ndq = (int)gridDim.x - ngemm;
        const long stride = (long)ndq * 512 * 8;
        float tv = NF4_TAB[lane & 15];
        for (long base = ((long)b * 512 + tid) * 8; base < (long)NELW; base += stride)
            dq8(dqc, dqa, dqo, base, tv);
        return;
    }

    const int w = tid >> 6;
    const int wm = w >> 2, wn = w & 3;           // 2M x 4N wave grid
    const int lrow = lane & 15, hi = lane >> 4;  // hi = k-chunk 0..3 (8 elems)
    const int key = lrow & 3;                    // read-side swizzle key

    const int nbm = M >> 8, nbn = N >> 8;
    const int cpx = (nbm * nbn) >> 3;            // ngemm%8==0 -> bijective
    int swz = ((int)blockIdx.x & 7) * cpx + ((int)blockIdx.x >> 3);
    const int bm = swz % nbm, bn = swz / nbm;    // bm fastest: B-panel reuse

    const long ldK = K;
    const int srow = tid >> 2;                   // 0..127 staging row
    const int scol = ((tid & 3) ^ (srow & 3)) * 8;   // pre-swizzled source col
    const unsigned short* gA = A + ((long)(bm * 256 + srow)) * ldK + scol;
    const unsigned short* gB = B + ((long)(bn * 256 + srow)) * ldK + scol;

    f32x4 acc[8][4];
    #pragma unroll
    for (int m = 0; m < 8; ++m)
        #pragma unroll
        for (int n = 0; n < 4; ++n) acc[m][n] = f32x4{0.f, 0.f, 0.f, 0.f};

    bf16x8 a0[4], a1[4], b0[2], b1[2];

    // stage half-tile h (0=A rows0-127, 1=A rows128-255, 2=B0, 3=B1) of K-step
    // kt into buffer b.  ONE 8KB global_load_lds (512thr x 16B).
    auto STAGE = [&](int kt, int h, int b) {
        const unsigned short* src = ((h >> 1) ? gB : gA)
            + (long)((h & 1) * 128) * ldK + (long)kt * 32;
        char* dst = (char*)&lds[b][h >> 1][h & 1][0] + w * 1024;
        __builtin_amdgcn_global_load_lds((gptr_t)src, (lptr_t)dst, 16, 0, 0);
    };
    // lane's A fragments: which=0 -> rows 0-63 of wave's half, 1 -> rows 64-127
    auto LDA = [&](bf16x8 (&fr)[4], int which, int b) {
        const unsigned short* base = &lds[b][0][wm][0];
        #pragma unroll
        for (int m = 0; m < 4; ++m)
            fr[m] = *(const bf16x8*)(base + (which * 64 + m * 16 + lrow) * 32
                                     + ((hi ^ key) * 8));
    };
    // lane's B fragments: which=0 -> n0..1, 1 -> n2..3
    auto LDB = [&](bf16x8 (&fr)[2], int which, int b) {
        const unsigned short* base = &lds[b][1][wn >> 1][0];
        #pragma unroll
        for (int n = 0; n < 2; ++n)
            fr[n] = *(const bf16x8*)(base + ((wn & 1) * 64 + (which * 2 + n) * 16 + lrow) * 32
                                     + ((hi ^ key) * 8));
    };
    auto MMA = [&](bf16x8 (&fa)[4], bf16x8 (&fb)[2], int mo, int no) {
        __builtin_amdgcn_s_setprio(1);
        #pragma unroll
        for (int m = 0; m < 4; ++m)
            #pragma unroll
            for (int n = 0; n < 2; ++n)
                acc[mo + m][no + n] = __builtin_amdgcn_mfma_f32_16x16x32_bf16(
                    fa[m], fb[n], acc[mo + m][no + n], 0, 0, 0);
        __builtin_amdgcn_s_setprio(0);
    };
    // s_barrier + sched fence for memory classes (ALU/VALU/SALU/MFMA may cross)
    #define BAR() do { __builtin_amdgcn_s_barrier(); \
                       __builtin_amdgcn_sched_barrier(0xF); } while (0)

    const int NT = K >> 5;
    // ---- prologue: tile0 fully + A-halves of tile1; publish tile0, THEN read
    STAGE(0, 0, 0); STAGE(0, 1, 0); STAGE(0, 2, 0); STAGE(0, 3, 0);
    STAGE(1, 0, 1); STAGE(1, 1, 1);
    asm volatile("s_waitcnt vmcnt(2)" ::: "memory");   // tile0's 4 loads landed
    BAR();                                             // ...in every wave
    LDA(a0, 0, 0);

    int cur = 0;
    for (int t = 0; t < NT - 1; ++t) {
        const int nb = cur ^ 1;
        const int tA = (t + 2 < NT) ? t + 2 : NT - 1;  // clamped: dupes land dead
        // P1: read b0[t] AND a1[t] (a1 feeds P2); issue B0[t+1]
        STAGE(t + 1, 2, nb);
        LDB(b0, 0, cur);
        LDA(a1, 1, cur);
        MMA(a0, b0, 0, 0);
        BAR();
        // P2: no reads — MMA(a1,b0) runs on P1's reads while DS pipe is free
        STAGE(t + 1, 3, nb);
        MMA(a1, b0, 4, 0);
        BAR();
        // P3: read b1[t]; issue A0[t+2]; publish A[t+1] (vmcnt 3)
        STAGE(tA, 0, cur);
        LDB(b1, 1, cur);
        MMA(a0, b1, 0, 2);
        asm volatile("s_waitcnt vmcnt(3)" ::: "memory");
        BAR();
        // P4: read a0[t+1] (published at P3 barrier); MMA(a1,b1) on prior reads
        STAGE(tA, 1, cur);
        LDA(a0, 0, nb);
        MMA(a1, b1, 4, 2);
        asm volatile("s_waitcnt vmcnt(2)" ::: "memory");
        BAR();
        cur = nb;
    }
    // ---- epilogue: last K-step, fully published by final P3/P4 waits ----
    LDB(b0, 0, cur);
    LDA(a1, 1, cur);
    MMA(a0, b0, 0, 0);
    MMA(a1, b0, 4, 0);
    LDB(b1, 1, cur);
    MMA(a0, b1, 0, 2);
    MMA(a1, b1, 4, 2);
    #undef BAR

    // ---- C write.  C/D layout: col = lane&15, row = (lane>>4)*4 + reg ----
    const int grow = bm * 256 + wm * 128 + hi * 4;
    const int gcol = bn * 256 + wn * 64 + lrow;
    if (MODE == 0) {
        float* C = (float*)Cout;
        #pragma unroll
        for (int m = 0; m < 8; ++m)
            #pragma unroll
            for (int n = 0; n < 4; ++n)
                #pragma unroll
                for (int r = 0; r < 4; ++r)
                    C[(long)(grow + m * 16 + r) * N + gcol + n * 16] = acc[m][n][r];
    } else if (MODE == 1) {
        unsigned short* C = (unsigned short*)Cout;
        #pragma unroll
        for (int m = 0; m < 8; ++m)
            #pragma unroll
            for (int n = 0; n < 4; ++n)
                #pragma unroll
                for (int r = 0; r < 4; ++r)
                    C[(long)(grow + m * 16 + r) * N + gcol + n * 16] = f2bf(acc[m][n][r]);
    } else {
        // fused SwiGLU: C holds h1 (bf16); acc = h3. write silu(h1)*h3 in place
        unsigned short* C = (unsigned short*)Cout;
        #pragma unroll
        for (int m = 0; m < 8; ++m)
            #pragma unroll
            for (int n = 0; n < 4; ++n)
                #pragma unroll
                for (int r = 0; r < 4; ++r) {
                    long idx = (long)(grow + m * 16 + r) * N + gcol + n * 16;
                    float h1v = bf2f(C[idx]);
                    float g = h1v / (1.0f + __expf(-h1v));
                    C[idx] = f2bf(g * acc[m][n][r]);
                }
    }
}

// ---- workspace layout (bytes) ----
//  [0)          W1 bf16 (90,177,536)
//  [90177536)   W3 bf16 (90,177,536)  -- later reused for W2
//  [180355072)  x  bf16 (33,554,432)
//  [213909504)  h1 bf16 (90,177,536)  -- fused swiglu written in-place by GEMM2
//  total 304,087,040
#define WS_NEEDED 304087040UL
#define DQBLK 512     // tail dequant blocks appended to GEMM1/GEMM2 dispatches

extern "C" void kernel_launch(void* const* d_in, const int* in_sizes, int n_in,
                              void* d_out, int out_size, void* d_ws, size_t ws_size,
                              hipStream_t stream) {
    const float* x   = (const float*)d_in[0];
    const int*   w1c = (const int*)d_in[1];
    const float* w1a = (const float*)d_in[2];
    const int*   w2c = (const int*)d_in[3];
    const float* w2a = (const float*)d_in[4];
    const int*   w3c = (const int*)d_in[5];
    const float* w3a = (const float*)d_in[6];

    if (ws_size < WS_NEEDED) return;   // fail loudly via validation

    char* ws = (char*)d_ws;
    unsigned short* W1 = (unsigned short*)(ws);
    unsigned short* W3 = (unsigned short*)(ws + 90177536);   // also W2 later
    unsigned short* Xb = (unsigned short*)(ws + 180355072);
    unsigned short* H1 = (unsigned short*)(ws + 213909504);

    // preamble: W1 dequant + x cast (one dispatch)
    pre_k<<<PREBLK, 256, 0, stream>>>(w1c, w1a, W1, x, Xb);

    const int g12 = (MTOK / 256) * (HID / 256);   // 688
    const int g3  = (MTOK / 256) * (DIM / 256);   // 256

    // h1 = x @ W1^T; tail blocks dequant W3 -> consumed by NEXT dispatch
    gemm256_k<1><<<g12 + DQBLK, 512, 0, stream>>>(Xb, W1, H1, MTOK, HID, DIM,
                                                  g12, w3c, w3a, W3);
    // h = silu(h1) * (x @ W3^T) in-place; tail blocks dequant W2 into W1's buf
    // (GEMM1 retired at dispatch boundary; this dispatch reads only Xb/W3/H1)
    gemm256_k<2><<<g12 + DQBLK, 512, 0, stream>>>(Xb, W3, H1, MTOK, HID, DIM,
                                                  g12, w2c, w2a, W1);
    // out = h @ W2^T (W2 lives in W1's buffer), fp32 output
    gemm256_k<0><<<g3, 512, 0, stream>>>(H1, W1, (float*)d_out, MTOK, DIM, HID,
                                         g3, nullptr, nullptr, nullptr);
}

// Round 16
// 1411.641 us; speedup vs baseline: 8.5091x; 8.5091x over previous
//
#include <hip/hip_runtime.h>
#include <hip/hip_bf16.h>
#include <stdint.h>

// ---- problem dims (fixed by setup_inputs) ----
#define DIM   4096
#define HID   11008
#define MTOK  4096              // B*S = 2*2048
#define NELW  (HID * DIM)       // 45,088,768 elements per weight matrix

typedef __bf16 bf16x8 __attribute__((ext_vector_type(8)));
typedef float  f32x4  __attribute__((ext_vector_type(4)));
using gptr_t = const __attribute__((address_space(1))) void*;
using lptr_t = __attribute__((address_space(3))) void*;

__device__ __forceinline__ float bf2f(unsigned short u) {
    unsigned int t = ((unsigned int)u) << 16;
    float f; __builtin_memcpy(&f, &t, 4); return f;
}
__device__ __forceinline__ unsigned short f2bf(float f) {   // RNE
    unsigned int x; __builtin_memcpy(&x, &f, 4);
    x += 0x7fffu + ((x >> 16) & 1u);
    return (unsigned short)(x >> 16);
}

__device__ __constant__ float NF4_TAB[16] = {
    -1.0f, -0.6961928009986877f, -0.5250730514526367f, -0.39491748809814453f,
    -0.28444138169288635f, -0.18477343022823334f, -0.09105003625154495f, 0.0f,
    0.07958029955625534f, 0.16093020141124725f, 0.24611230194568634f,
    0.33791524171829224f, 0.44070982933044434f, 0.5626170039176941f,
    0.6989939212799072f, 1.0f};

// dequant 8 codes at element offset `base` (table via wave shfl from lanes 0-15)
__device__ __forceinline__ void dq8(const int* codes, const float* absmax,
                                    unsigned short* out, long base, float tv)
{
    int4 c0 = *(const int4*)(codes + base);
    int4 c1 = *(const int4*)(codes + base + 4);
    float s = absmax[base >> 6];
    union { uint4 q; unsigned short u[8]; } o;
    o.u[0] = f2bf(__shfl(tv, c0.x) * s);
    o.u[1] = f2bf(__shfl(tv, c0.y) * s);
    o.u[2] = f2bf(__shfl(tv, c0.z) * s);
    o.u[3] = f2bf(__shfl(tv, c0.w) * s);
    o.u[4] = f2bf(__shfl(tv, c1.x) * s);
    o.u[5] = f2bf(__shfl(tv, c1.y) * s);
    o.u[6] = f2bf(__shfl(tv, c1.z) * s);
    o.u[7] = f2bf(__shfl(tv, c1.w) * s);
    *(uint4*)(out + base) = o.q;
}

// preamble: blocks [0, 22016) dequant W1; blocks [22016, 30208) cast x->bf16
#define W1BLK 22016
#define PREBLK (W1BLK + (MTOK * DIM) / 2048)
__global__ __launch_bounds__(256) void pre_k(
    const int* __restrict__ w1c, const float* __restrict__ w1a,
    unsigned short* __restrict__ W1,
    const float* __restrict__ x, unsigned short* __restrict__ Xb)
{
    float tv = NF4_TAB[threadIdx.x & 15];
    if ((int)blockIdx.x < W1BLK) {
        long base = ((long)blockIdx.x * 256 + threadIdx.x) * 8;
        dq8(w1c, w1a, W1, base, tv);
    } else {
        long base = ((long)(blockIdx.x - W1BLK) * 256 + threadIdx.x) * 8;
        float4 a = *(const float4*)(x + base);
        float4 b = *(const float4*)(x + base + 4);
        union { uint4 q; unsigned short u[8]; } o;
        o.u[0] = f2bf(a.x); o.u[1] = f2bf(a.y); o.u[2] = f2bf(a.z); o.u[3] = f2bf(a.w);
        o.u[4] = f2bf(b.x); o.u[5] = f2bf(b.y); o.u[6] = f2bf(b.z); o.u[7] = f2bf(b.w);
        *(uint4*)(Xb + base) = o.q;
    }
}

// ============================================================================
// R16: 256x128 tile, BK=32, 48KB LDS, ~115 regs -> 2 blocks/CU (m114 test).
//
// R15 failure: 256^2 tile needs ~220 regs; launch_bounds(512,4) capped at 128
// -> accumulator spilled (WRITE 10.6GB, MfmaUtil 3.5%).  Also key=lrow&3 at
// BK=32 is a 4-way bank conflict.  R16 shrinks the TILE so the state fits:
//   tile 256(M) x 128(N), BK=32; 8 waves = 4M x 2N, per-wave 64x64 out;
//   acc[4][4] f32x4 = 64 AGPR + a[4] 16 + b 8 + addr ~25 = ~115 <= 128 ✓
//   LDS [2buf][A0,A1,B][128x32] = 48KB; 2 blocks/CU (VGPR-bound).
// Mechanism under test (m114): two INDEPENDENT co-resident blocks co-schedule
// MFMA and DS pipes (block A's MFMA overlaps block B's reads) — the overlap
// barrier-aligned single-block scheduling could not produce (R5-R13).
//
// Swizzle (4 chunks of 16B per 64B row; row stride = 16 banks):
//   LDS[r][c] = G[r][c ^ ((r>>1)&3)], read chunk = hi ^ ((lrow>>1)&3).
//   Bank map verified: each hi-group's 16 lanes hit starts
//   {0,16,4,20,8,24,12,28}x2 -> 2 lanes/bank = conflict-free (m136).
//
// LEDGER (2 phases/K-step, stages 2 ahead, one vmcnt per step):
//   prologue: A0[0],A1[0],B[0]->buf0, A0[1],A1[1]->buf1 (5); vmcnt(2) lands
//     tile0; BAR.  In-flight entering loop: A[1] x2.
//   iter t (cur=t&1, nb=cur^1):
//     P1: read a[4],b01[2] from cur; STAGE B[t+1]->nb; MMA(a,b01); BAR
//     P2: read b23[2] from cur; STAGE A0[t+2],A1[t+2]->cur; MMA(a,b23);
//         vmcnt(2); BAR
//   vmcnt(2)@P2: in-flight = A[t+1](2,oldest) B[t+1](1) A[t+2](2) = 5 ->
//     drains through B[t+1]: tile t+1 fully published.  ✓
//   Liveness: P1's B-stage->nb: b-reads of nb drained by t-1's MMAs before
//     t-1 P2 BAR (>=1 bar).  P2's A-stages->cur: a-reads drained by P1's MMA
//     before P1 BAR (1 bar).  Reads of tile t: published at t-1 P2 vmcnt+BAR.
//   Tail: t=NT-2's A-stage clamps to NT-1 -> dupes land in buf[(NT-2)&1]
//     (epilogue reads buf[(NT-1)&1] — dead).  Real A[NT-1] staged at t=NT-3
//     into (NT-3)&1 = (NT-1)&1 ✓.  Epilogue: no stages, all published.
//   NT = K/32 (128/128/344), NT>=3 ✓.  Barriers/K-elem = same as R14.
//
// Blocks >= ngemm run grid-stride NF4 dequant (tail fill; consumer = next
// dispatch).  MODE: 0=f32 out, 1=bf16 out, 2=bf16 fused silu(Cout)*acc.
// Requires M%256==0, N%128==0, K%32==0, grid%8==0 (all hold).
// ============================================================================
template<int MODE>
__global__ __launch_bounds__(512, 4) void gemm256_k(
    const unsigned short* __restrict__ A, const unsigned short* __restrict__ B,
    void* __restrict__ Cout, int M, int N, int K, int ngemm,
    const int* __restrict__ dqc, const float* __restrict__ dqa,
    unsigned short* __restrict__ dqo)
{
    __shared__ __align__(16) unsigned short lds[2][3][128 * 32];

    const int tid = threadIdx.x;
    const int lane = tid & 63;

    if ((int)blockIdx.x >= ngemm) {          // ---- tail: grid-stride dequant
        if (!dqo) return;
        const int b = (int)blockIdx.x - ngemm;
        const int ndq = (int)gridDim.x - ngemm;
        const long stride = (long)ndq * 512 * 8;
        float tv = NF4_TAB[lane & 15];
        for (long base = ((long)b * 512 + tid) * 8; base < (long)NELW; base += stride)
            dq8(dqc, dqa, dqo, base, tv);
        return;
    }

    const int w = tid >> 6;
    const int wm = w >> 1, wn = w & 1;           // 4M x 2N wave grid
    const int lrow = lane & 15, hi = lane >> 4;  // hi = k-chunk 0..3
    const int key = (lrow >> 1) & 3;             // read-side swizzle key

    const int nbm = M >> 8, nbn = N >> 7;
    const int cpx = (nbm * nbn) >> 3;            // ngemm%8==0 -> bijective
    int swz = ((int)blockIdx.x & 7) * cpx + ((int)blockIdx.x >> 3);
    const int bm = swz % nbm, bn = swz / nbm;    // bm fastest: B-panel reuse

    const long ldK = K;
    const int srow = tid >> 2;                   // 0..127 staging row
    const int scol = ((tid & 3) ^ ((srow >> 1) & 3)) * 8;  // pre-swizzled col
    const unsigned short* gA = A + ((long)(bm * 256 + srow)) * ldK + scol;
    const unsigned short* gB = B + ((long)(bn * 128 + srow)) * ldK + scol;

    f32x4 acc[4][4];
    #pragma unroll
    for (int m = 0; m < 4; ++m)
        #pragma unroll
        for (int n = 0; n < 4; ++n) acc[m][n] = f32x4{0.f, 0.f, 0.f, 0.f};

    bf16x8 a[4], b01[2], b23[2];

    // stage region h (0=A rows0-127, 1=A rows128-255, 2=B) of K-step kt
    // into buffer bb.  ONE 8KB global_load_lds (512thr x 16B, linear dest).
    auto STAGE = [&](int kt, int h, int bb) {
        const unsigned short* src = (h == 2 ? gB : gA + (long)(h * 128) * ldK)
                                    + (long)kt * 32;
        char* dst = (char*)&lds[bb][h][0] + w * 1024;
        __builtin_amdgcn_global_load_lds((gptr_t)src, (lptr_t)dst, 16, 0, 0);
    };
    // wave's A fragments: region wm>>1, local rows (wm&1)*64 + m*16 + lrow
    auto LDA4 = [&](int bb) {
        const unsigned short* base = &lds[bb][wm >> 1][0];
        #pragma unroll
        for (int m = 0; m < 4; ++m)
            a[m] = *(const bf16x8*)(base + ((wm & 1) * 64 + m * 16 + lrow) * 32
                                    + ((hi ^ key) * 8));
    };
    // wave's B fragments: rows wn*64 + (which*2+n)*16 + lrow of region 2
    auto LDB2 = [&](bf16x8 (&fb)[2], int which, int bb) {
        const unsigned short* base = &lds[bb][2][0];
        #pragma unroll
        for (int n = 0; n < 2; ++n)
            fb[n] = *(const bf16x8*)(base + (wn * 64 + (which * 2 + n) * 16 + lrow) * 32
                                     + ((hi ^ key) * 8));
    };
    auto MMA2 = [&](bf16x8 (&fb)[2], int no) {
        __builtin_amdgcn_s_setprio(1);
        #pragma unroll
        for (int m = 0; m < 4; ++m)
            #pragma unroll
            for (int n = 0; n < 2; ++n)
                acc[m][no + n] = __builtin_amdgcn_mfma_f32_16x16x32_bf16(
                    a[m], fb[n], acc[m][no + n], 0, 0, 0);
        __builtin_amdgcn_s_setprio(0);
    };
    // s_barrier + sched fence for memory classes (ALU/VALU/SALU/MFMA may cross)
    #define BAR() do { __builtin_amdgcn_s_barrier(); \
                       __builtin_amdgcn_sched_barrier(0xF); } while (0)

    const int NT = K >> 5;
    // ---- prologue: tile0 fully -> buf0; A-halves of tile1 -> buf1
    STAGE(0, 0, 0); STAGE(0, 1, 0); STAGE(0, 2, 0);
    STAGE(1, 0, 1); STAGE(1, 1, 1);
    asm volatile("s_waitcnt vmcnt(2)" ::: "memory");   // tile0's 3 loads landed
    BAR();

    for (int t = 0; t < NT - 1; ++t) {
        const int cur = t & 1, nb = cur ^ 1;
        const int tA = (t + 2 < NT) ? t + 2 : NT - 1;  // clamped: dupes land dead
        // P1: read a[4], b01 from cur; stage B[t+1]->nb; MMA lower-n half
        LDA4(cur);
        LDB2(b01, 0, cur);
        STAGE(t + 1, 2, nb);
        MMA2(b01, 0);
        BAR();
        // P2: read b23 from cur; stage A0/A1[t+2]->cur; MMA upper-n half;
        //     vmcnt(2) publishes tile t+1
        LDB2(b23, 1, cur);
        STAGE(tA, 0, cur);
        STAGE(tA, 1, cur);
        MMA2(b23, 2);
        asm volatile("s_waitcnt vmcnt(2)" ::: "memory");
        BAR();
    }
    // ---- epilogue: tile NT-1, fully published ----
    {
        const int pb = (NT - 1) & 1;
        LDA4(pb);
        LDB2(b01, 0, pb);
        MMA2(b01, 0);
        LDB2(b23, 1, pb);
        MMA2(b23, 2);
    }
    #undef BAR

    // ---- C write.  C/D layout: col = lane&15, row = (lane>>4)*4 + reg ----
    const int grow = bm * 256 + wm * 64 + hi * 4;
    const int gcol = bn * 128 + wn * 64 + lrow;
    if (MODE == 0) {
        float* C = (float*)Cout;
        #pragma unroll
        for (int m = 0; m < 4; ++m)
            #pragma unroll
            for (int n = 0; n < 4; ++n)
                #pragma unroll
                for (int r = 0; r < 4; ++r)
                    C[(long)(grow + m * 16 + r) * N + gcol + n * 16] = acc[m][n][r];
    } else if (MODE == 1) {
        unsigned short* C = (unsigned short*)Cout;
        #pragma unroll
        for (int m = 0; m < 4; ++m)
            #pragma unroll
            for (int n = 0; n < 4; ++n)
                #pragma unroll
                for (int r = 0; r < 4; ++r)
                    C[(long)(grow + m * 16 + r) * N + gcol + n * 16] = f2bf(acc[m][n][r]);
    } else {
        // fused SwiGLU: C holds h1 (bf16); acc = h3. write silu(h1)*h3 in place
        unsigned short* C = (unsigned short*)Cout;
        #pragma unroll
        for (int m = 0; m < 4; ++m)
            #pragma unroll
            for (int n = 0; n < 4; ++n)
                #pragma unroll
                for (int r = 0; r < 4; ++r) {
                    long idx = (long)(grow + m * 16 + r) * N + gcol + n * 16;
                    float h1v = bf2f(C[idx]);
                    float g = h1v / (1.0f + __expf(-h1v));
                    C[idx] = f2bf(g * acc[m][n][r]);
                }
    }
}

// ---- workspace layout (bytes) ----
//  [0)          W1 bf16 (90,177,536)
//  [90177536)   W3 bf16 (90,177,536)  -- later reused for W2
//  [180355072)  x  bf16 (33,554,432)
//  [213909504)  h1 bf16 (90,177,536)  -- fused swiglu written in-place by GEMM2
//  total 304,087,040
#define WS_NEEDED 304087040UL
#define DQBLK 512     // tail dequant blocks appended to GEMM1/GEMM2 dispatches

extern "C" void kernel_launch(void* const* d_in, const int* in_sizes, int n_in,
                              void* d_out, int out_size, void* d_ws, size_t ws_size,
                              hipStream_t stream) {
    const float* x   = (const float*)d_in[0];
    const int*   w1c = (const int*)d_in[1];
    const float* w1a = (const float*)d_in[2];
    const int*   w2c = (const int*)d_in[3];
    const float* w2a = (const float*)d_in[4];
    const int*   w3c = (const int*)d_in[5];
    const float* w3a = (const float*)d_in[6];

    if (ws_size < WS_NEEDED) return;   // fail loudly via validation

    char* ws = (char*)d_ws;
    unsigned short* W1 = (unsigned short*)(ws);
    unsigned short* W3 = (unsigned short*)(ws + 90177536);   // also W2 later
    unsigned short* Xb = (unsigned short*)(ws + 180355072);
    unsigned short* H1 = (unsigned short*)(ws + 213909504);

    // preamble: W1 dequant + x cast (one dispatch)
    pre_k<<<PREBLK, 256, 0, stream>>>(w1c, w1a, W1, x, Xb);

    const int g12 = (MTOK / 256) * (HID / 128);   // 1376
    const int g3  = (MTOK / 256) * (DIM / 128);   // 512

    // h1 = x @ W1^T; tail blocks dequant W3 -> consumed by NEXT dispatch
    gemm256_k<1><<<g12 + DQBLK, 512, 0, stream>>>(Xb, W1, H1, MTOK, HID, DIM,
                                                  g12, w3c, w3a, W3);
    // h = silu(h1) * (x @ W3^T) in-place; tail blocks dequant W2 into W1's buf
    // (GEMM1 retired at dispatch boundary; this dispatch reads only Xb/W3/H1)
    gemm256_k<2><<<g12 + DQBLK, 512, 0, stream>>>(Xb, W3, H1, MTOK, HID, DIM,
                                                  g12, w2c, w2a, W1);
    // out = h @ W2^T (W2 lives in W1's buffer), fp32 output
    gemm256_k<0><<<g3, 512, 0, stream>>>(H1, W1, (float*)d_out, MTOK, DIM, HID,
                                         g3, nullptr, nullptr, nullptr);
}

// Round 17
// 1108.593 us; speedup vs baseline: 10.8352x; 1.2734x over previous
//
#include <hip/hip_runtime.h>
#include <hip/hip_bf16.h>
#include <stdint.h>

// ---- problem dims (fixed by setup_inputs) ----
#define DIM   4096
#define HID   11008
#define MTOK  4096              // B*S = 2*2048
#define NELW  (HID * DIM)       // 45,088,768 elements per weight matrix

typedef __bf16 bf16x8 __attribute__((ext_vector_type(8)));
typedef float  f32x4  __attribute__((ext_vector_type(4)));
using gptr_t = const __attribute__((address_space(1))) void*;
using lptr_t = __attribute__((address_space(3))) void*;

__device__ __forceinline__ float bf2f(unsigned short u) {
    unsigned int t = ((unsigned int)u) << 16;
    float f; __builtin_memcpy(&f, &t, 4); return f;
}
__device__ __forceinline__ unsigned short f2bf(float f) {   // RNE
    unsigned int x; __builtin_memcpy(&x, &f, 4);
    x += 0x7fffu + ((x >> 16) & 1u);
    return (unsigned short)(x >> 16);
}

__device__ __constant__ float NF4_TAB[16] = {
    -1.0f, -0.6961928009986877f, -0.5250730514526367f, -0.39491748809814453f,
    -0.28444138169288635f, -0.18477343022823334f, -0.09105003625154495f, 0.0f,
    0.07958029955625534f, 0.16093020141124725f, 0.24611230194568634f,
    0.33791524171829224f, 0.44070982933044434f, 0.5626170039176941f,
    0.6989939212799072f, 1.0f};

// dequant 8 codes at element offset `base` (table via wave shfl from lanes 0-15)
__device__ __forceinline__ void dq8(const int* codes, const float* absmax,
                                    unsigned short* out, long base, float tv)
{
    int4 c0 = *(const int4*)(codes + base);
    int4 c1 = *(const int4*)(codes + base + 4);
    float s = absmax[base >> 6];
    union { uint4 q; unsigned short u[8]; } o;
    o.u[0] = f2bf(__shfl(tv, c0.x) * s);
    o.u[1] = f2bf(__shfl(tv, c0.y) * s);
    o.u[2] = f2bf(__shfl(tv, c0.z) * s);
    o.u[3] = f2bf(__shfl(tv, c0.w) * s);
    o.u[4] = f2bf(__shfl(tv, c1.x) * s);
    o.u[5] = f2bf(__shfl(tv, c1.y) * s);
    o.u[6] = f2bf(__shfl(tv, c1.z) * s);
    o.u[7] = f2bf(__shfl(tv, c1.w) * s);
    *(uint4*)(out + base) = o.q;
}

// preamble: blocks [0, 22016) dequant W1; blocks [22016, 30208) cast x->bf16
#define W1BLK 22016
#define PREBLK (W1BLK + (MTOK * DIM) / 2048)
__global__ __launch_bounds__(256) void pre_k(
    const int* __restrict__ w1c, const float* __restrict__ w1a,
    unsigned short* __restrict__ W1,
    const float* __restrict__ x, unsigned short* __restrict__ Xb)
{
    float tv = NF4_TAB[threadIdx.x & 15];
    if ((int)blockIdx.x < W1BLK) {
        long base = ((long)blockIdx.x * 256 + threadIdx.x) * 8;
        dq8(w1c, w1a, W1, base, tv);
    } else {
        long base = ((long)(blockIdx.x - W1BLK) * 256 + threadIdx.x) * 8;
        float4 a = *(const float4*)(x + base);
        float4 b = *(const float4*)(x + base + 4);
        union { uint4 q; unsigned short u[8]; } o;
        o.u[0] = f2bf(a.x); o.u[1] = f2bf(a.y); o.u[2] = f2bf(a.z); o.u[3] = f2bf(a.w);
        o.u[4] = f2bf(b.x); o.u[5] = f2bf(b.y); o.u[6] = f2bf(b.z); o.u[7] = f2bf(b.w);
        *(uint4*)(Xb + base) = o.q;
    }
}

// ============================================================================
// 256x256-tile 4-phase/K-tile GEMM — R17 = R14 = R10 (session best, 1104us,
// reproduced 1108us).  Final configuration.
//
// Session conclusions baked into this kernel:
//   +  T1 XCD-swizzle (bijective, bm-fastest B-panel reuse)
//   +  T2 both-sides LDS XOR swizzle (bank conflicts 1.35e8 -> 0)
//   +  T3/T4 4-phase counted-vmcnt schedule (never drains to 0 in-loop)
//   +  T5 setprio around MFMA clusters
//   +  single barrier per phase (R9, +2%), a1-read re-phased into P1 (R10)
//   +  dispatch fusion: dequant rides GEMM tail blocks (R7, −30us)
//   −  refuted on this workload: 2x unroll/static-cur (spills), 32x32 MFMA
//      (bank conflicts + dep chains), m201 lgkm0 phase discipline (null),
//      2-blocks/CU via BK=32 (spill) or 256x128 tile (traffic > overlap)
//
// vmcnt LEDGER (r3/r4-derived, HW-verified in R9/R10/R14):
//   prologue: tile0 A0,A1,B0,B1 -> buf0; tile1 A0,A1 -> buf1 (12 loads);
//     vmcnt(4) lands tile0; BAR; LDA(a0,0,0).
//   iter t: P1 stage B0[t+1]->nb, P2 B1[t+1]->nb, P3 A0[t+2]->cur + vmcnt(6)
//     publishes A[t+1], P4 A1[t+2]->cur + vmcnt(4) publishes B[t+1].
//     In-flight never <4 (T4).
//   Region liveness (regions = M-half for A, N-pair for B): every overwrite
//     >=1 barrier after its region's last read drained; P4's a0[t+1] read
//     follows P3's vmcnt(6)+BAR publish.  Tail clamps land in dead regions.
//
// Blocks >= ngemm run grid-stride NF4 dequant (dqc/dqa->dqo) -- tail fill;
// consumer is the NEXT dispatch (dispatch boundary = fence).
// MODE: 0 = f32 out, 1 = bf16 out, 2 = bf16 fused h=silu(Cout)*acc in-place.
// ============================================================================
template<int MODE>
__global__ __launch_bounds__(512, 2) void gemm256_k(
    const unsigned short* __restrict__ A, const unsigned short* __restrict__ B,
    void* __restrict__ Cout, int M, int N, int K, int ngemm,
    const int* __restrict__ dqc, const float* __restrict__ dqa,
    unsigned short* __restrict__ dqo)
{
    __shared__ __align__(16) unsigned short lds[2][2][2][128 * 64];

    const int tid = threadIdx.x;
    const int lane = tid & 63;

    if ((int)blockIdx.x >= ngemm) {          // ---- tail: grid-stride dequant
        if (!dqo) return;
        const int b = (int)blockIdx.x - ngemm;
        const int ndq = (int)gridDim.x - ngemm;
        const long stride = (long)ndq * 512 * 8;
        float tv = NF4_TAB[lane & 15];
        for (long base = ((long)b * 512 + tid) * 8; base < (long)NELW; base += stride)
            dq8(dqc, dqa, dqo, base, tv);
        return;
    }

    const int w = tid >> 6;
    const int wm = w >> 2, wn = w & 3;           // 2M x 4N wave grid
    const int lrow = lane & 15, hi = lane >> 4;
    const int key = lrow & 7;                    // read-side swizzle key

    const int nbm = M >> 8, nbn = N >> 8;
    const int cpx = (nbm * nbn) >> 3;            // ngemm%8==0 -> bijective
    int swz = ((int)blockIdx.x & 7) * cpx + ((int)blockIdx.x >> 3);
    const int bm = swz % nbm, bn = swz / nbm;    // bm fastest: B-panel reuse

    const long ldK = K;
    const int srow = tid >> 3;                   // 0..63 staging row
    const int scol = ((tid & 7) ^ (srow & 7)) * 8;   // pre-swizzled source col
    const unsigned short* gA = A + ((long)(bm * 256 + srow)) * ldK + scol;
    const unsigned short* gB = B + ((long)(bn * 256 + srow)) * ldK + scol;

    f32x4 acc[8][4];
    #pragma unroll
    for (int m = 0; m < 8; ++m)
        #pragma unroll
        for (int n = 0; n < 4; ++n) acc[m][n] = f32x4{0.f, 0.f, 0.f, 0.f};

    bf16x8 a0[4][2], a1[4][2], b0[2][2], b1[2][2];

    // stage half-tile h (0=A rows0-127, 1=A rows128-255, 2=B0, 3=B1) of K-tile
    auto STAGE = [&](int kt, int h, int b) {
        const unsigned short* src = ((h >> 1) ? gB : gA)
            + (long)((h & 1) * 128) * ldK + (long)kt * 64;
        char* dst = (char*)&lds[b][h >> 1][h & 1][0] + w * 1024;
        __builtin_amdgcn_global_load_lds((gptr_t)src, (lptr_t)dst, 16, 0, 0);
        __builtin_amdgcn_global_load_lds((gptr_t)(src + (long)64 * ldK),
                                         (lptr_t)(dst + 8192), 16, 0, 0);
    };
    // lane's A fragments: which=0 -> rows 0-63 of wave's half, 1 -> rows 64-127
    auto LDA = [&](bf16x8 (&fr)[4][2], int which, int b) {
        const unsigned short* base = &lds[b][0][wm][0];
        #pragma unroll
        for (int m = 0; m < 4; ++m)
            #pragma unroll
            for (int ks = 0; ks < 2; ++ks)
                fr[m][ks] = *(const bf16x8*)(base + (which * 64 + m * 16 + lrow) * 64
                                             + (((ks * 4 + hi) ^ key) * 8));
    };
    // lane's B fragments: which=0 -> n0..1, 1 -> n2..3
    auto LDB = [&](bf16x8 (&fr)[2][2], int which, int b) {
        const unsigned short* base = &lds[b][1][wn >> 1][0];
        #pragma unroll
        for (int n = 0; n < 2; ++n)
            #pragma unroll
            for (int ks = 0; ks < 2; ++ks)
                fr[n][ks] = *(const bf16x8*)(base + ((wn & 1) * 64 + (which * 2 + n) * 16 + lrow) * 64
                                             + (((ks * 4 + hi) ^ key) * 8));
    };
    auto MMA = [&](bf16x8 (&fa)[4][2], bf16x8 (&fb)[2][2], int mo, int no) {
        __builtin_amdgcn_s_setprio(1);
        #pragma unroll
        for (int m = 0; m < 4; ++m)
            #pragma unroll
            for (int n = 0; n < 2; ++n)
                #pragma unroll
                for (int ks = 0; ks < 2; ++ks)
                    acc[mo + m][no + n] = __builtin_amdgcn_mfma_f32_16x16x32_bf16(
                        fa[m][ks], fb[n][ks], acc[mo + m][no + n], 0, 0, 0);
        __builtin_amdgcn_s_setprio(0);
    };
    // s_barrier + sched fence for memory classes (ALU/VALU/SALU/MFMA may cross)
    #define BAR() do { __builtin_amdgcn_s_barrier(); \
                       __builtin_amdgcn_sched_barrier(0xF); } while (0)

    const int NT = K >> 6;
    // ---- prologue: tile0 fully + A-halves of tile1; publish tile0, THEN read
    STAGE(0, 0, 0); STAGE(0, 1, 0); STAGE(0, 2, 0); STAGE(0, 3, 0);
    STAGE(1, 0, 1); STAGE(1, 1, 1);
    asm volatile("s_waitcnt vmcnt(4)" ::: "memory");   // own tile0 loads landed
    BAR();                                             // ...and everyone else's
    LDA(a0, 0, 0);

    int cur = 0;
    for (int t = 0; t < NT - 1; ++t) {
        const int nb = cur ^ 1;
        const int tA = (t + 2 < NT) ? t + 2 : NT - 1;  // clamped: dupes land dead
        // P1: read b0[t] AND a1[t] (a1 feeds P2); issue B0[t+1]
        STAGE(t + 1, 2, nb);
        LDB(b0, 0, cur);
        LDA(a1, 1, cur);
        MMA(a0, b0, 0, 0);
        BAR();
        // P2: no reads — MMA(a1,b0) runs on P1's reads while DS pipe is free
        STAGE(t + 1, 3, nb);
        MMA(a1, b0, 4, 0);
        BAR();
        // P3: read b1[t]; issue A0[t+2]; publish A[t+1] (vmcnt 6)
        STAGE(tA, 0, cur);
        LDB(b1, 1, cur);
        MMA(a0, b1, 0, 2);
        asm volatile("s_waitcnt vmcnt(6)" ::: "memory");
        BAR();
        // P4: read a0[t+1] (published at P3 barrier); MMA(a1,b1) on prior reads
        STAGE(tA, 1, cur);
        LDA(a0, 0, nb);
        MMA(a1, b1, 4, 2);
        asm volatile("s_waitcnt vmcnt(4)" ::: "memory");
        BAR();
        cur = nb;
    }
    // ---- epilogue: last tile, fully published by final P3/P4 waits ----
    LDB(b0, 0, cur);
    LDA(a1, 1, cur);
    MMA(a0, b0, 0, 0);
    MMA(a1, b0, 4, 0);
    LDB(b1, 1, cur);
    MMA(a0, b1, 0, 2);
    MMA(a1, b1, 4, 2);
    #undef BAR

    // ---- C write.  C/D layout: col = lane&15, row = (lane>>4)*4 + reg ----
    const int grow = bm * 256 + wm * 128 + hi * 4;
    const int gcol = bn * 256 + wn * 64 + lrow;
    if (MODE == 0) {
        float* C = (float*)Cout;
        #pragma unroll
        for (int m = 0; m < 8; ++m)
            #pragma unroll
            for (int n = 0; n < 4; ++n)
                #pragma unroll
                for (int r = 0; r < 4; ++r)
                    C[(long)(grow + m * 16 + r) * N + gcol + n * 16] = acc[m][n][r];
    } else if (MODE == 1) {
        unsigned short* C = (unsigned short*)Cout;
        #pragma unroll
        for (int m = 0; m < 8; ++m)
            #pragma unroll
            for (int n = 0; n < 4; ++n)
                #pragma unroll
                for (int r = 0; r < 4; ++r)
                    C[(long)(grow + m * 16 + r) * N + gcol + n * 16] = f2bf(acc[m][n][r]);
    } else {
        // fused SwiGLU: C holds h1 (bf16); acc = h3. write silu(h1)*h3 in place
        unsigned short* C = (unsigned short*)Cout;
        #pragma unroll
        for (int m = 0; m < 8; ++m)
            #pragma unroll
            for (int n = 0; n < 4; ++n)
                #pragma unroll
                for (int r = 0; r < 4; ++r) {
                    long idx = (long)(grow + m * 16 + r) * N + gcol + n * 16;
                    float h1v = bf2f(C[idx]);
                    float g = h1v / (1.0f + __expf(-h1v));
                    C[idx] = f2bf(g * acc[m][n][r]);
                }
    }
}

// ---- workspace layout (bytes) ----
//  [0)          W1 bf16 (90,177,536)
//  [90177536)   W3 bf16 (90,177,536)  -- later reused for W2
//  [180355072)  x  bf16 (33,554,432)
//  [213909504)  h1 bf16 (90,177,536)  -- fused swiglu written in-place by GEMM2
//  total 304,087,040
#define WS_NEEDED 304087040UL
#define DQBLK 512     // tail dequant blocks appended to GEMM1/GEMM2 dispatches

extern "C" void kernel_launch(void* const* d_in, const int* in_sizes, int n_in,
                              void* d_out, int out_size, void* d_ws, size_t ws_size,
                              hipStream_t stream) {
    const float* x   = (const float*)d_in[0];
    const int*   w1c = (const int*)d_in[1];
    const float* w1a = (const float*)d_in[2];
    const int*   w2c = (const int*)d_in[3];
    const float* w2a = (const float*)d_in[4];
    const int*   w3c = (const int*)d_in[5];
    const float* w3a = (const float*)d_in[6];

    if (ws_size < WS_NEEDED) return;   // fail loudly via validation

    char* ws = (char*)d_ws;
    unsigned short* W1 = (unsigned short*)(ws);
    unsigned short* W3 = (unsigned short*)(ws + 90177536);   // also W2 later
    unsigned short* Xb = (unsigned short*)(ws + 180355072);
    unsigned short* H1 = (unsigned short*)(ws + 213909504);

    // preamble: W1 dequant + x cast (one dispatch)
    pre_k<<<PREBLK, 256, 0, stream>>>(w1c, w1a, W1, x, Xb);

    const int g12 = (MTOK / 256) * (HID / 256);   // 688
    const int g3  = (MTOK / 256) * (DIM / 256);   // 256

    // h1 = x @ W1^T; tail blocks dequant W3 -> consumed by NEXT dispatch
    gemm256_k<1><<<g12 + DQBLK, 512, 0, stream>>>(Xb, W1, H1, MTOK, HID, DIM,
                                                  g12, w3c, w3a, W3);
    // h = silu(h1) * (x @ W3^T) in-place; tail blocks dequant W2 into W1's buf
    // (GEMM1 retired at dispatch boundary; this dispatch reads only Xb/W3/H1)
    gemm256_k<2><<<g12 + DQBLK, 512, 0, stream>>>(Xb, W3, H1, MTOK, HID, DIM,
                                                  g12, w2c, w2a, W1);
    // out = h @ W2^T (W2 lives in W1's buffer), fp32 output
    gemm256_k<0><<<g3, 512, 0, stream>>>(H1, W1, (float*)d_out, MTOK, DIM, HID,
                                         g3, nullptr, nullptr, nullptr);
}